// Round 1
// 2664.662 us; speedup vs baseline: 1.5645x; 1.5645x over previous
//
#include <hip/hip_runtime.h>
#include <hip/hip_bf16.h>

#define D 10000
#define NROWS 16384
#define NC 100
#define NCP 112   // padded class dim: 7 tiles of 16
#define BKH 40    // padded K stride in halves (80 B) -> conflict-free frag reads
#define BM 256    // rows per block
#define KSPLIT 8

typedef __attribute__((ext_vector_type(8))) short short8;
typedef __attribute__((ext_vector_type(4))) float f32x4;
typedef __attribute__((ext_vector_type(4))) unsigned short us4;

__device__ __forceinline__ unsigned short bf16_of(float f) {
  __hip_bfloat16 b = __float2bfloat16(f);
  return __builtin_bit_cast(unsigned short, b);
}
__device__ __forceinline__ float f32_of(unsigned short u) {
  unsigned int x = ((unsigned int)u) << 16;
  return __builtin_bit_cast(float, x);
}

// ------------------------------------------------------------------
// K0: split class_hvs fp32 -> bf16 hi/lo pair (one-time, 4 MB total).
// hhi/hlo live in the out_hv region (overwritten later by k_update).
// ------------------------------------------------------------------
__global__ __launch_bounds__(256) void k_split_hv(
    const float* __restrict__ hv, unsigned short* __restrict__ hhi,
    unsigned short* __restrict__ hlo) {
  int i = (blockIdx.x * 256 + threadIdx.x) * 4;
  if (i < NC * D) {
    float4 v = *(const float4*)&hv[i];
    float f0 = v.x, f1 = v.y, f2 = v.z, f3 = v.w;
    unsigned short h0 = bf16_of(f0), h1 = bf16_of(f1), h2 = bf16_of(f2), h3 = bf16_of(f3);
    us4 hh = {h0, h1, h2, h3};
    us4 hl = {bf16_of(f0 - f32_of(h0)), bf16_of(f1 - f32_of(h1)),
              bf16_of(f2 - f32_of(h2)), bf16_of(f3 - f32_of(h3))};
    *(us4*)&hhi[i] = hh;
    *(us4*)&hlo[i] = hl;
  }
}

// ------------------------------------------------------------------
// K1: scores via MFMA bf16 3-term fp32 emulation.
//   D = Ahi*Bhi + Alo*Bhi + Ahi*Blo  (rel err ~2^-16 per product)
// BM=256 rows x NCP=112 cols per block, 4 waves x (64 rows x 112 cols)
// = 4x7 16x16 tiles/wave. K-split 8 across blockIdx.y, partial sums
// merged by global atomicAdd into zeroed scores.
// A converted fp32->bf16 pair on the fly during LDS staging (A read
// exactly once from HBM -> kernel is HBM-bound at ~104 us floor).
// ------------------------------------------------------------------
__global__ __launch_bounds__(256, 2) void k_gemm(
    const float* __restrict__ enc, const unsigned short* __restrict__ hhi,
    const unsigned short* __restrict__ hlo, float* __restrict__ scores) {
  __shared__ unsigned short Ah[BM * BKH];   // 20480 B
  __shared__ unsigned short Al[BM * BKH];   // 20480 B
  __shared__ unsigned short Bh[NCP * BKH];  //  8960 B
  __shared__ unsigned short Bl[NCP * BKH];  //  8960 B  (total 58880 B -> 2 blk/CU)

  const int tid = threadIdx.x;
  const int lane = tid & 63;
  const int wave = tid >> 6;
  const size_t r0 = (size_t)blockIdx.x * BM;
  const int kb = blockIdx.y;

  // 313 chunks of K=32 (tail zero-padded): kb0 gets 40, kb1..7 get 39
  const int ch0 = (kb == 0) ? 0 : (40 + (kb - 1) * 39);
  const int cnt = (kb == 0) ? 40 : 39;

  f32x4 acc[4][7];
#pragma unroll
  for (int mt = 0; mt < 4; ++mt)
#pragma unroll
    for (int nt = 0; nt < 7; ++nt) acc[mt][nt] = {0.f, 0.f, 0.f, 0.f};

  const int arow = tid >> 3;        // 0..31
  const int acol = (tid & 7) * 4;   // 0..28
  const int bn = tid >> 1;          // 0..111 for tid<224
  const int bkoff = (tid & 1) * 16; // 0 or 16

  for (int ch = 0; ch < cnt; ++ch) {
    const int k0 = (ch0 + ch) * 32;
    __syncthreads();  // previous chunk's frag reads done

    // ---- stage A: 256 rows x 32 k, convert fp32 -> bf16 hi/lo
#pragma unroll
    for (int rr = 0; rr < 8; ++rr) {
      const int row = arow + rr * 32;
      float4 v;
      if (k0 + acol + 3 < D)
        v = *(const float4*)&enc[(r0 + row) * (size_t)D + (k0 + acol)];
      else
        v = make_float4(0.f, 0.f, 0.f, 0.f);
      unsigned short h0 = bf16_of(v.x), h1 = bf16_of(v.y),
                     h2 = bf16_of(v.z), h3 = bf16_of(v.w);
      us4 hh = {h0, h1, h2, h3};
      us4 hl = {bf16_of(v.x - f32_of(h0)), bf16_of(v.y - f32_of(h1)),
                bf16_of(v.z - f32_of(h2)), bf16_of(v.w - f32_of(h3))};
      *(us4*)&Ah[row * BKH + acol] = hh;
      *(us4*)&Al[row * BKH + acol] = hl;
    }

    // ---- stage B transposed [n][k]: 112 rows x 32 k (rows>=100 zero)
    if (tid < 224) {
      const int kk = k0 + bkoff;
      uint4 b0h = make_uint4(0, 0, 0, 0), b1h = b0h, b0l = b0h, b1l = b0h;
      if (bn < NC && kk + 15 < D) {
        const unsigned short* ph = hhi + (size_t)bn * D + kk;
        const unsigned short* pl = hlo + (size_t)bn * D + kk;
        b0h = *(const uint4*)ph;
        b1h = *(const uint4*)(ph + 8);
        b0l = *(const uint4*)pl;
        b1l = *(const uint4*)(pl + 8);
      }
      *(uint4*)&Bh[bn * BKH + bkoff] = b0h;
      *(uint4*)&Bh[bn * BKH + bkoff + 8] = b1h;
      *(uint4*)&Bl[bn * BKH + bkoff] = b0l;
      *(uint4*)&Bl[bn * BKH + bkoff + 8] = b1l;
    }
    __syncthreads();  // stores visible

    // ---- fragments + MFMA
    const int fr = lane & 15;
    const int ko = (lane >> 4) * 8;
    short8 ah[4], alr[4];
#pragma unroll
    for (int mt = 0; mt < 4; ++mt) {
      const int base = (wave * 64 + mt * 16 + fr) * BKH + ko;
      ah[mt] = *(const short8*)&Ah[base];
      alr[mt] = *(const short8*)&Al[base];
    }
#pragma unroll
    for (int nt = 0; nt < 7; ++nt) {
      const int bb = (nt * 16 + fr) * BKH + ko;
      short8 bhf = *(const short8*)&Bh[bb];
      short8 blf = *(const short8*)&Bl[bb];
#pragma unroll
      for (int mt = 0; mt < 4; ++mt) {
        acc[mt][nt] = __builtin_amdgcn_mfma_f32_16x16x32_bf16(ah[mt], bhf, acc[mt][nt], 0, 0, 0);
        acc[mt][nt] = __builtin_amdgcn_mfma_f32_16x16x32_bf16(alr[mt], bhf, acc[mt][nt], 0, 0, 0);
        acc[mt][nt] = __builtin_amdgcn_mfma_f32_16x16x32_bf16(ah[mt], blf, acc[mt][nt], 0, 0, 0);
      }
    }
  }

  // ---- epilogue: C/D layout col=lane&15, row=(lane>>4)*4+reg
#pragma unroll
  for (int mt = 0; mt < 4; ++mt) {
    const size_t rb = r0 + wave * 64 + mt * 16 + ((lane >> 4) * 4);
#pragma unroll
    for (int nt = 0; nt < 7; ++nt) {
      const int col = nt * 16 + (lane & 15);
      if (col < NC) {
#pragma unroll
        for (int i = 0; i < 4; ++i)
          unsafeAtomicAdd(&scores[(rb + i) * NC + col], acc[mt][nt][i]);
      }
    }
  }
}

// ------------------------------------------------------------------
// K2: per-row argmax over 100 classes -> misclassified pred/target.
// ------------------------------------------------------------------
__global__ __launch_bounds__(256) void k_argmax(
    const float* __restrict__ scores, const int* __restrict__ tgt,
    int* __restrict__ predm, int* __restrict__ targm) {
  const int row = blockIdx.x * 256 + threadIdx.x;
  const float* s = scores + (size_t)row * NC;
  float m = -3.4e38f;
  int mi = 0;
#pragma unroll
  for (int q = 0; q < 25; ++q) {
    float4 v = *(const float4*)&s[q * 4];
    if (v.x > m) { m = v.x; mi = q * 4 + 0; }
    if (v.y > m) { m = v.y; mi = q * 4 + 1; }
    if (v.z > m) { m = v.z; mi = q * 4 + 2; }
    if (v.w > m) { m = v.w; mi = q * 4 + 3; }
  }
  const int t = tgt[row];
  const bool mis = (mi != t);
  predm[row] = mis ? mi : -1;
  targm[row] = mis ? t : -1;
}

// ------------------------------------------------------------------
// K3: segment sums of misclassified rows (unchanged this round —
// isolating the k_scores rewrite; counters next round will expose
// this kernel's true cost).
// ------------------------------------------------------------------
__global__ __launch_bounds__(256) void k_scatter(
    const float* __restrict__ enc, const int* __restrict__ predm,
    const int* __restrict__ targm, float* __restrict__ add,
    float* __restrict__ sub) {
  __shared__ float aacc[NC * 64];
  __shared__ float sacc[NC * 64];
  const int tid = threadIdx.x;
  for (int i = tid; i < NC * 64; i += 256) { aacc[i] = 0.f; sacc[i] = 0.f; }
  __syncthreads();

  const int lane = tid & 63;
  const int wave = tid >> 6;
  const int colbase = blockIdx.x * 64;
  const int col = colbase + lane;
  const bool cv = (col < D);
  const int rbase = blockIdx.y * 2048 + wave * 512;

  for (int i = 0; i < 512; i += 4) {
    int r = rbase + i;
    int t0 = targm[r + 0], t1 = targm[r + 1], t2 = targm[r + 2], t3 = targm[r + 3];
    int p0 = predm[r + 0], p1 = predm[r + 1], p2 = predm[r + 2], p3 = predm[r + 3];
    float v0 = cv ? enc[(size_t)(r + 0) * D + col] : 0.f;
    float v1 = cv ? enc[(size_t)(r + 1) * D + col] : 0.f;
    float v2 = cv ? enc[(size_t)(r + 2) * D + col] : 0.f;
    float v3 = cv ? enc[(size_t)(r + 3) * D + col] : 0.f;
    if (t0 >= 0) { unsafeAtomicAdd(&aacc[t0 * 64 + lane], v0); unsafeAtomicAdd(&sacc[p0 * 64 + lane], v0); }
    if (t1 >= 0) { unsafeAtomicAdd(&aacc[t1 * 64 + lane], v1); unsafeAtomicAdd(&sacc[p1 * 64 + lane], v1); }
    if (t2 >= 0) { unsafeAtomicAdd(&aacc[t2 * 64 + lane], v2); unsafeAtomicAdd(&sacc[p2 * 64 + lane], v2); }
    if (t3 >= 0) { unsafeAtomicAdd(&aacc[t3 * 64 + lane], v3); unsafeAtomicAdd(&sacc[p3 * 64 + lane], v3); }
  }
  __syncthreads();

  for (int i = tid; i < NC * 64; i += 256) {
    int c = i >> 6, cc = i & 63;
    int gcol = colbase + cc;
    if (gcol < D) {
      unsafeAtomicAdd(&add[(size_t)c * D + gcol], aacc[i]);
      unsafeAtomicAdd(&sub[(size_t)c * D + gcol], sacc[i]);
    }
  }
}

// ------------------------------------------------------------------
// K4: new_class_hvs = class_hvs + clip(add,-1,1) - clip(sub,-1,1)
// ------------------------------------------------------------------
__global__ __launch_bounds__(256) void k_update(
    const float* __restrict__ hv, const float* __restrict__ add,
    const float* __restrict__ sub, float* __restrict__ outhv) {
  int base = (blockIdx.x * 256 + threadIdx.x) * 4;
  if (base < NC * D) {
    float4 a = *(const float4*)&add[base];
    float4 s = *(const float4*)&sub[base];
    float4 h = *(const float4*)&hv[base];
    float4 o;
    o.x = h.x + fminf(fmaxf(a.x, -1.f), 1.f) - fminf(fmaxf(s.x, -1.f), 1.f);
    o.y = h.y + fminf(fmaxf(a.y, -1.f), 1.f) - fminf(fmaxf(s.y, -1.f), 1.f);
    o.z = h.z + fminf(fmaxf(a.z, -1.f), 1.f) - fminf(fmaxf(s.z, -1.f), 1.f);
    o.w = h.w + fminf(fmaxf(a.w, -1.f), 1.f) - fminf(fmaxf(s.w, -1.f), 1.f);
    *(float4*)&outhv[base] = o;
  }
}

extern "C" void kernel_launch(void* const* d_in, const int* in_sizes, int n_in,
                              void* d_out, int out_size, void* d_ws, size_t ws_size,
                              hipStream_t stream) {
  const float* enc = (const float*)d_in[0];
  const int* tgt = (const int*)d_in[1];
  const float* hv = (const float*)d_in[2];
  float* out = (float*)d_out;  // [16384*100 scores][100*10000 new_class_hvs]
  float* scores = out;
  float* outhv = out + (size_t)NROWS * NC;
  // bf16 hi/lo split of class_hvs parked in the out_hv region (4 MB),
  // consumed by k_gemm, then overwritten by k_update at the end.
  unsigned short* hhi = (unsigned short*)outhv;        // 2 MB
  unsigned short* hlo = hhi + (size_t)NC * D;          // 2 MB

  char* ws = (char*)d_ws;
  int* predm = (int*)ws;                         // 65536 B
  int* targm = (int*)(ws + 65536);               // 65536 B
  float* add = (float*)(ws + 131072);            // 4,000,000 B
  float* sub = (float*)(ws + 131072 + 4000000);  // 4,000,000 B

  hipMemsetAsync(add, 0, 8000000, stream);
  hipMemsetAsync(scores, 0, (size_t)NROWS * NC * 4, stream);  // atomic accum target

  k_split_hv<<<dim3((NC * D / 4 + 255) / 256), dim3(256), 0, stream>>>(hv, hhi, hlo);
  k_gemm<<<dim3(NROWS / BM, KSPLIT), dim3(256), 0, stream>>>(enc, hhi, hlo, scores);
  k_argmax<<<dim3(NROWS / 256), dim3(256), 0, stream>>>(scores, tgt, predm, targm);
  k_scatter<<<dim3((D + 63) / 64, 8), dim3(256), 0, stream>>>(enc, predm, targm, add, sub);
  k_update<<<dim3((NC * D / 4 + 255) / 256), dim3(256), 0, stream>>>(hv, add, sub, outhv);
}

// Round 2
// 1348.683 us; speedup vs baseline: 3.0910x; 1.9758x over previous
//
#include <hip/hip_runtime.h>

#define D 10000
#define NROWS 16384
#define NC 100
#define NCP 112   // padded class dim: 7 tiles of 16
#define BKH 40    // LDS K stride in shorts (80 B): b128-aligned, 2-way-max frag reads
#define BM 256    // rows per gemm block
#define KSPLIT 8
#define SRS 72    // scatter LDS stride in shorts (64 rows + 8 pad)

typedef __attribute__((ext_vector_type(8))) short short8;
typedef __attribute__((ext_vector_type(4))) float f32x4;
typedef __attribute__((ext_vector_type(4))) unsigned short us4;
typedef __attribute__((ext_vector_type(8))) unsigned short us8;

// branchless round-to-nearest-even fp32 -> bf16 (inputs finite)
__device__ __forceinline__ unsigned short bf16rne(float f) {
  unsigned u = __builtin_bit_cast(unsigned, f);
  u += 0x7FFFu + ((u >> 16) & 1u);
  return (unsigned short)(u >> 16);
}
__device__ __forceinline__ float f32_of(unsigned short u) {
  unsigned x = ((unsigned)u) << 16;
  return __builtin_bit_cast(float, x);
}

// ------------------------------------------------------------------
// K0: split class_hvs fp32 -> bf16 hi/lo planes (one-time, 4 MB).
// ------------------------------------------------------------------
__global__ __launch_bounds__(256) void k_split_hv(
    const float* __restrict__ hv, unsigned short* __restrict__ hhi,
    unsigned short* __restrict__ hlo) {
  int i = (blockIdx.x * 256 + threadIdx.x) * 4;
  if (i < NC * D) {
    float4 v = *(const float4*)&hv[i];
    unsigned short h0 = bf16rne(v.x), h1 = bf16rne(v.y),
                   h2 = bf16rne(v.z), h3 = bf16rne(v.w);
    us4 hh = {h0, h1, h2, h3};
    us4 hl = {bf16rne(v.x - f32_of(h0)), bf16rne(v.y - f32_of(h1)),
              bf16rne(v.z - f32_of(h2)), bf16rne(v.w - f32_of(h3))};
    *(us4*)&hhi[i] = hh;
    *(us4*)&hlo[i] = hl;
  }
}

// ------------------------------------------------------------------
// K1: scores via MFMA bf16 3-term fp32 emulation.
// v2: 512 threads (8 waves), per-wave tile 2x7 -> acc=56 VGPR (was 112;
// spill suspicion on v1). launch_bounds(512,4) caps VGPR at 128 for
// 16 waves/CU (2 blocks).
// ------------------------------------------------------------------
__global__ __launch_bounds__(512, 4) void k_gemm(
    const float* __restrict__ enc, const unsigned short* __restrict__ hhi,
    const unsigned short* __restrict__ hlo, float* __restrict__ scores) {
  __shared__ unsigned short Ah[BM * BKH];   // 20480 B
  __shared__ unsigned short Al[BM * BKH];   // 20480 B
  __shared__ unsigned short Bh[NCP * BKH];  //  8960 B
  __shared__ unsigned short Bl[NCP * BKH];  //  8960 B

  const int tid = threadIdx.x;
  const int lane = tid & 63;
  const int wave = tid >> 6;  // 0..7, owns rows [32w, 32w+32)
  const size_t r0 = (size_t)blockIdx.x * BM;
  const int kb = blockIdx.y;
  const int ch0 = (kb == 0) ? 0 : (40 + (kb - 1) * 39);
  const int cnt = (kb == 0) ? 40 : 39;

  f32x4 acc[2][7];
#pragma unroll
  for (int mt = 0; mt < 2; ++mt)
#pragma unroll
    for (int nt = 0; nt < 7; ++nt) acc[mt][nt] = {0.f, 0.f, 0.f, 0.f};

  const int arow = tid >> 3;         // 0..63
  const int acol4 = (tid & 7) * 4;   // 0..28
  const int bn = tid >> 1;           // 0..111 for tid<224
  const int bkoff = (tid & 1) * 16;

  for (int ch = 0; ch < cnt; ++ch) {
    const int k0 = (ch0 + ch) * 32;
    __syncthreads();

    // ---- stage A: 256 rows x 32 k, fp32 -> bf16 hi/lo
#pragma unroll
    for (int g = 0; g < 4; ++g) {
      const int row = arow + g * 64;
      float4 v;
      if (k0 + acol4 < D)   // D%4==0 => whole float4 in-bounds
        v = *(const float4*)&enc[(r0 + row) * (size_t)D + (k0 + acol4)];
      else
        v = make_float4(0.f, 0.f, 0.f, 0.f);
      unsigned short h0 = bf16rne(v.x), h1 = bf16rne(v.y),
                     h2 = bf16rne(v.z), h3 = bf16rne(v.w);
      us4 hh = {h0, h1, h2, h3};
      us4 hl = {bf16rne(v.x - f32_of(h0)), bf16rne(v.y - f32_of(h1)),
                bf16rne(v.z - f32_of(h2)), bf16rne(v.w - f32_of(h3))};
      *(us4*)&Ah[row * BKH + acol4] = hh;
      *(us4*)&Al[row * BKH + acol4] = hl;
    }

    // ---- stage B [n][k]: 112 x 32 (rows >= 100 zero)
    if (tid < 224) {
      const int kk = k0 + bkoff;
      uint4 b0h = make_uint4(0, 0, 0, 0), b1h = b0h, b0l = b0h, b1l = b0h;
      if (bn < NC && kk + 15 < D) {
        const unsigned short* ph = hhi + (size_t)bn * D + kk;
        const unsigned short* pl = hlo + (size_t)bn * D + kk;
        b0h = *(const uint4*)ph;
        b1h = *(const uint4*)(ph + 8);
        b0l = *(const uint4*)pl;
        b1l = *(const uint4*)(pl + 8);
      }
      *(uint4*)&Bh[bn * BKH + bkoff] = b0h;
      *(uint4*)&Bh[bn * BKH + bkoff + 8] = b1h;
      *(uint4*)&Bl[bn * BKH + bkoff] = b0l;
      *(uint4*)&Bl[bn * BKH + bkoff + 8] = b1l;
    }
    __syncthreads();

    // ---- fragments + MFMA
    const int fr = lane & 15;
    const int ko = (lane >> 4) * 8;
    short8 ah[2], alr[2];
#pragma unroll
    for (int mt = 0; mt < 2; ++mt) {
      const int base = (wave * 32 + mt * 16 + fr) * BKH + ko;
      ah[mt] = *(const short8*)&Ah[base];
      alr[mt] = *(const short8*)&Al[base];
    }
#pragma unroll
    for (int nt = 0; nt < 7; ++nt) {
      const int bb = (nt * 16 + fr) * BKH + ko;
      short8 bhf = *(const short8*)&Bh[bb];
      short8 blf = *(const short8*)&Bl[bb];
#pragma unroll
      for (int mt = 0; mt < 2; ++mt) {
        acc[mt][nt] = __builtin_amdgcn_mfma_f32_16x16x32_bf16(ah[mt], bhf, acc[mt][nt], 0, 0, 0);
        acc[mt][nt] = __builtin_amdgcn_mfma_f32_16x16x32_bf16(alr[mt], bhf, acc[mt][nt], 0, 0, 0);
        acc[mt][nt] = __builtin_amdgcn_mfma_f32_16x16x32_bf16(ah[mt], blf, acc[mt][nt], 0, 0, 0);
      }
    }
  }

  // ---- epilogue: C layout col=lane&15, row=(lane>>4)*4+i
#pragma unroll
  for (int mt = 0; mt < 2; ++mt) {
    const size_t rb = r0 + wave * 32 + mt * 16 + ((lane >> 4) * 4);
#pragma unroll
    for (int nt = 0; nt < 7; ++nt) {
      const int col = nt * 16 + (lane & 15);
      if (col < NC) {
#pragma unroll
        for (int i = 0; i < 4; ++i)
          unsafeAtomicAdd(&scores[(rb + i) * NC + col], acc[mt][nt][i]);
      }
    }
  }
}

// ------------------------------------------------------------------
// K2: per-row argmax over 100 classes -> misclassified pred/target.
// ------------------------------------------------------------------
__global__ __launch_bounds__(256) void k_argmax(
    const float* __restrict__ scores, const int* __restrict__ tgt,
    int* __restrict__ predm, int* __restrict__ targm) {
  const int row = blockIdx.x * 256 + threadIdx.x;
  const float* s = scores + (size_t)row * NC;
  float m = -3.4e38f;
  int mi = 0;
#pragma unroll
  for (int q = 0; q < 25; ++q) {
    float4 v = *(const float4*)&s[q * 4];
    if (v.x > m) { m = v.x; mi = q * 4 + 0; }
    if (v.y > m) { m = v.y; mi = q * 4 + 1; }
    if (v.z > m) { m = v.z; mi = q * 4 + 2; }
    if (v.w > m) { m = v.w; mi = q * 4 + 3; }
  }
  const int t = tgt[row];
  const bool mis = (mi != t);
  predm[row] = mis ? mi : -1;
  targm[row] = mis ? t : -1;
}

// ------------------------------------------------------------------
// K3: fused scatter+update as one-hot MFMA GEMM.
//   add[c][d] = sum_r 1[targm==c]*enc[r][d];  sub with predm.
//   outhv = hv + clip(add) - clip(sub)  written directly (no atomics,
//   no add/sub workspace, no k_update).
// Block: 32 d-cols, all 256 class-slots (128 add + 128 sub), K=16384
// in 64-row chunks, register-prefetch double buffer. enc split to
// bf16 hi/lo during staging (exact one-hot => error ~1e-4).
// Wave w holds add & sub accs for classes {16w..16w+15, 64+16w..64+16w+15}.
// ------------------------------------------------------------------
__global__ __launch_bounds__(256, 4) void k_scatter_mfma(
    const float* __restrict__ enc, const int* __restrict__ predm,
    const int* __restrict__ targm, const float* __restrict__ hv,
    float* __restrict__ outhv) {
  __shared__ unsigned short Eh[32 * SRS];  // 4608 B, d-major [d][r]
  __shared__ unsigned short El[32 * SRS];  // 4608 B
  __shared__ int keyT[64];
  __shared__ int keyP[64];

  const int tid = threadIdx.x;
  const int lane = tid & 63;
  const int wave = tid >> 6;  // 0..3
  const int d0 = blockIdx.x * 32;

  const int dd = tid & 31;         // this thread's d column
  const int rg8 = (tid >> 5) * 8;  // 8-row group base
  const bool cv = (d0 + dd) < D;

  f32x4 aA[2][2], aS[2][2];  // [class group][n-tile]
#pragma unroll
  for (int g = 0; g < 2; ++g)
#pragma unroll
    for (int nt = 0; nt < 2; ++nt) { aA[g][nt] = {0.f, 0.f, 0.f, 0.f}; aS[g][nt] = {0.f, 0.f, 0.f, 0.f}; }

  // prefetch chunk 0 (8 k-rows of this thread's column + keys)
  float pe[8];
#pragma unroll
  for (int i = 0; i < 8; ++i)
    pe[i] = cv ? enc[(size_t)(rg8 + i) * D + d0 + dd] : 0.f;
  int pk = 0;
  if (tid < 64) pk = targm[tid];
  else if (tid < 128) pk = predm[tid - 64];

  const int NIT = NROWS / 64;  // 256 chunks
  for (int it = 0; it < NIT; ++it) {
    __syncthreads();  // prior chunk's frag reads done

    // ---- stage: convert prefetched column to bf16 hi/lo, write transposed
    {
      us8 hh, hl;
#pragma unroll
      for (int i = 0; i < 8; ++i) {
        unsigned short h = bf16rne(pe[i]);
        hh[i] = h;
        hl[i] = bf16rne(pe[i] - f32_of(h));
      }
      *(us8*)&Eh[dd * SRS + rg8] = hh;   // 16B aligned: 144*dd + 16*(tid>>5)
      *(us8*)&El[dd * SRS + rg8] = hl;
    }
    if (tid < 64) keyT[tid] = pk;
    else if (tid < 128) keyP[tid - 64] = pk;
    __syncthreads();  // stores visible

    // ---- prefetch next chunk (in flight during MFMA below)
    if (it + 1 < NIT) {
      const size_t kn = (size_t)(it + 1) * 64;
#pragma unroll
      for (int i = 0; i < 8; ++i)
        pe[i] = cv ? enc[(kn + rg8 + i) * D + d0 + dd] : 0.f;
      if (tid < 64) pk = targm[kn + tid];
      else if (tid < 128) pk = predm[kn + tid - 64];
    }

    // ---- compute: 2 K-steps of 32 rows
    const int fr = lane & 15;
    const int ko = (lane >> 4) * 8;
    const int c0 = wave * 16 + fr;
    const int c1 = 64 + wave * 16 + fr;
#pragma unroll
    for (int ks = 0; ks < 64; ks += 32) {
      int kk[8], pp[8];
      *(int4*)&kk[0] = *(const int4*)&keyT[ks + ko];
      *(int4*)&kk[4] = *(const int4*)&keyT[ks + ko + 4];
      *(int4*)&pp[0] = *(const int4*)&keyP[ks + ko];
      *(int4*)&pp[4] = *(const int4*)&keyP[ks + ko + 4];
      short8 fA0, fA1, fS0, fS1;
#pragma unroll
      for (int j = 0; j < 8; ++j) {
        fA0[j] = (kk[j] == c0) ? (short)0x3F80 : (short)0;
        fA1[j] = (kk[j] == c1) ? (short)0x3F80 : (short)0;
        fS0[j] = (pp[j] == c0) ? (short)0x3F80 : (short)0;
        fS1[j] = (pp[j] == c1) ? (short)0x3F80 : (short)0;
      }
#pragma unroll
      for (int nt = 0; nt < 2; ++nt) {
        const int bb = (nt * 16 + fr) * SRS + ks + ko;
        short8 bh = *(const short8*)&Eh[bb];
        short8 bl = *(const short8*)&El[bb];
        aA[0][nt] = __builtin_amdgcn_mfma_f32_16x16x32_bf16(fA0, bh, aA[0][nt], 0, 0, 0);
        aA[0][nt] = __builtin_amdgcn_mfma_f32_16x16x32_bf16(fA0, bl, aA[0][nt], 0, 0, 0);
        aA[1][nt] = __builtin_amdgcn_mfma_f32_16x16x32_bf16(fA1, bh, aA[1][nt], 0, 0, 0);
        aA[1][nt] = __builtin_amdgcn_mfma_f32_16x16x32_bf16(fA1, bl, aA[1][nt], 0, 0, 0);
        aS[0][nt] = __builtin_amdgcn_mfma_f32_16x16x32_bf16(fS0, bh, aS[0][nt], 0, 0, 0);
        aS[0][nt] = __builtin_amdgcn_mfma_f32_16x16x32_bf16(fS0, bl, aS[0][nt], 0, 0, 0);
        aS[1][nt] = __builtin_amdgcn_mfma_f32_16x16x32_bf16(fS1, bh, aS[1][nt], 0, 0, 0);
        aS[1][nt] = __builtin_amdgcn_mfma_f32_16x16x32_bf16(fS1, bl, aS[1][nt], 0, 0, 0);
      }
    }
  }

  // ---- fused update epilogue: outhv = hv + clip(add) - clip(sub)
  const int rowoff = (lane >> 4) * 4;
#pragma unroll
  for (int g = 0; g < 2; ++g) {
    const int cb = g * 64 + wave * 16;
#pragma unroll
    for (int nt = 0; nt < 2; ++nt) {
      const int d = d0 + nt * 16 + (lane & 15);
      if (d < D) {
#pragma unroll
        for (int i = 0; i < 4; ++i) {
          const int c = cb + rowoff + i;
          if (c < NC) {
            const float a = aA[g][nt][i];
            const float s = aS[g][nt][i];
            outhv[(size_t)c * D + d] = hv[(size_t)c * D + d]
                + fminf(fmaxf(a, -1.f), 1.f) - fminf(fmaxf(s, -1.f), 1.f);
          }
        }
      }
    }
  }
}

extern "C" void kernel_launch(void* const* d_in, const int* in_sizes, int n_in,
                              void* d_out, int out_size, void* d_ws, size_t ws_size,
                              hipStream_t stream) {
  const float* enc = (const float*)d_in[0];
  const int* tgt = (const int*)d_in[1];
  const float* hv = (const float*)d_in[2];
  float* out = (float*)d_out;  // [16384*100 scores][100*10000 new_class_hvs]
  float* scores = out;
  float* outhv = out + (size_t)NROWS * NC;
  // bf16 hi/lo planes of class_hvs parked in outhv region (4 MB),
  // consumed by k_gemm, overwritten by k_scatter_mfma's epilogue after.
  unsigned short* hhi = (unsigned short*)outhv;  // 2 MB
  unsigned short* hlo = hhi + (size_t)NC * D;    // 2 MB

  char* ws = (char*)d_ws;
  int* predm = (int*)ws;            // 65536 B
  int* targm = (int*)(ws + 65536);  // 65536 B

  hipMemsetAsync(scores, 0, (size_t)NROWS * NC * 4, stream);  // atomic accum target

  k_split_hv<<<dim3((NC * D / 4 + 255) / 256), dim3(256), 0, stream>>>(hv, hhi, hlo);
  k_gemm<<<dim3(NROWS / BM, KSPLIT), dim3(512), 0, stream>>>(enc, hhi, hlo, scores);
  k_argmax<<<dim3(NROWS / 256), dim3(256), 0, stream>>>(scores, tgt, predm, targm);
  k_scatter_mfma<<<dim3((D + 31) / 32), dim3(256), 0, stream>>>(enc, predm, targm, hv, outhv);
}